// Round 1
// baseline (1020.143 us; speedup 1.0000x reference)
//
#include <hip/hip_runtime.h>

// PairwiseScore: out[i,j] = (ms[i] + ms[j] + MLP([g_i, g_j, g_i*g_j]))/3
// Decomposition: layer1 = A[i] + B[j] + (g_i*g_j) @ W1c
//   A[i,h] = g_i @ W1[0:256]   + b1[h]   (precomputed, ws)
//   B[j,h] = g_j @ W1[256:512]           (precomputed, ws)
//   W1c    = W1[512:768]
// Cuts layer-1 FLOPs 3x (230K -> 77K MACs/pair); total 32 GFLOP.

#define N  512
#define E  256
#define H  150
#define HP 160      // padded hidden
#define JB 32       // j-tile per block
#define EC 32       // e/k chunk size staged through LDS

// ---------------- kernel 1: precompute A, B into ws ----------------
// ws layout (floats): A[N][HP] at 0 ; B[N][HP] at N*HP
__global__ __launch_bounds__(256) void precompute_ab(
    const float* __restrict__ g, const float* __restrict__ W1,
    const float* __restrict__ b1, float* __restrict__ ws)
{
    const int i = blockIdx.x;
    __shared__ float gi[E];
    const int tid = threadIdx.x;
    if (tid < E) gi[tid] = g[i * E + tid];
    __syncthreads();
    if (tid < H) {
        float a = b1[tid], b = 0.0f;
        for (int e = 0; e < E; ++e) {
            const float ge = gi[e];
            a = fmaf(ge, W1[e * H + tid], a);
            b = fmaf(ge, W1[(E + e) * H + tid], b);
        }
        ws[i * HP + tid]       = a;
        ws[(N + i) * HP + tid] = b;
    }
}

// ---------------- kernel 2: fused pairwise MLP ----------------
// grid (N/JB, N): blockIdx.y = i, blockIdx.x = j-tile. 256 threads.
// Thread (tj=tid>>5, th=tid&31) owns 4 j's (tj*4..+3) x 5 h's (th*5..+4).
__global__ __launch_bounds__(256) void pairwise_main(
    const float* __restrict__ g,  const float* __restrict__ ms,
    const float* __restrict__ W1, const float* __restrict__ W2,
    const float* __restrict__ b2, const float* __restrict__ W3,
    const float* __restrict__ b3, const float* __restrict__ ws,
    float* __restrict__ out)
{
    const int i   = blockIdx.y;
    const int j0  = blockIdx.x * JB;
    const int tid = threadIdx.x;
    const int tj  = tid >> 5;   // 0..7
    const int th  = tid & 31;   // 0..31

    // LDS layout (floats), 11520 total = 46 KB -> 3 blocks/CU
    __shared__ float lds[11520];
    float* gi   = lds;                      // [0,256)           g row i
    float* wbuf = lds + 256;                // [256,5376)        W chunk [EC][HP]
    float* pbuf = lds + 256 + 5120;         // [5376,6400)       p chunk [JB][EC]
    float* h1   = lds + 256 + 5120 + 1024;  // [6400,11520)      h1 [JB][HP]
    float* h2   = lds + 256;                // alias wbuf: [JB] x stride 161 (bank-conflict-free)

    if (tid < E) gi[tid] = g[i * E + tid];
    __syncthreads();

    float acc[4][5];
#pragma unroll
    for (int q = 0; q < 4; ++q)
#pragma unroll
        for (int m = 0; m < 5; ++m) acc[q][m] = 0.0f;

    // ---- layer 1 bilinear term: (g_i * g_j) @ W1c ----
    for (int ec = 0; ec < E / EC; ++ec) {
        for (int idx = tid; idx < EC * HP; idx += 256) {
            const int e = idx / HP, h = idx - e * HP;
            wbuf[idx] = (h < H) ? W1[(2 * E + ec * EC + e) * H + h] : 0.0f;
        }
        for (int idx = tid; idx < JB * EC; idx += 256) {
            const int jl = idx >> 5, e5 = idx & 31;
            const int eg = ec * EC + e5;
            pbuf[idx] = g[(j0 + jl) * E + eg] * gi[eg];
        }
        __syncthreads();
#pragma unroll 4
        for (int kk = 0; kk < EC; ++kk) {
            float pj[4], wv[5];
#pragma unroll
            for (int q = 0; q < 4; ++q) pj[q] = pbuf[(tj * 4 + q) * EC + kk];
#pragma unroll
            for (int m = 0; m < 5; ++m) wv[m] = wbuf[kk * HP + th * 5 + m];
#pragma unroll
            for (int q = 0; q < 4; ++q)
#pragma unroll
                for (int m = 0; m < 5; ++m) acc[q][m] = fmaf(pj[q], wv[m], acc[q][m]);
        }
        __syncthreads();
    }

    // ---- layer-1 epilogue: h1 = relu(t + A[i] + B[j]) -> LDS ----
    {
        const float* Arow = ws + i * HP;
#pragma unroll
        for (int m = 0; m < 5; ++m) {
            const int h = th * 5 + m;
            const float a = (h < H) ? Arow[h] : 0.0f;
#pragma unroll
            for (int q = 0; q < 4; ++q) {
                const int jl = tj * 4 + q;
                float v = 0.0f;
                if (h < H) {
                    v = acc[q][m] + a + ws[(N + j0 + jl) * HP + h];
                    v = fmaxf(v, 0.0f);
                }
                h1[jl * HP + h] = v;
            }
        }
    }
    // no sync needed here: layer-2's post-load sync orders h1 writes before reads

    // ---- layer 2: h2 = relu(h1 @ W2 + b2) ----
    float acc2[4][5];
#pragma unroll
    for (int q = 0; q < 4; ++q)
#pragma unroll
        for (int m = 0; m < 5; ++m) acc2[q][m] = 0.0f;

    for (int kc = 0; kc < HP / EC; ++kc) {   // 5 chunks, zero-padded past 150
        for (int idx = tid; idx < EC * HP; idx += 256) {
            const int k = idx / HP, h = idx - k * HP;
            const int kg = kc * EC + k;
            wbuf[idx] = (h < H && kg < H) ? W2[kg * H + h] : 0.0f;
        }
        __syncthreads();
#pragma unroll 4
        for (int kk = 0; kk < EC; ++kk) {
            const int kg = kc * EC + kk;
            float hv[4], wv[5];
#pragma unroll
            for (int q = 0; q < 4; ++q) hv[q] = h1[(tj * 4 + q) * HP + kg];
#pragma unroll
            for (int m = 0; m < 5; ++m) wv[m] = wbuf[kk * HP + th * 5 + m];
#pragma unroll
            for (int q = 0; q < 4; ++q)
#pragma unroll
                for (int m = 0; m < 5; ++m) acc2[q][m] = fmaf(hv[q], wv[m], acc2[q][m]);
        }
        __syncthreads();
    }

    // ---- layer-2 epilogue: h2 (stride 161, aliases wbuf after final sync) ----
#pragma unroll
    for (int m = 0; m < 5; ++m) {
        const int h = th * 5 + m;
        const float bb = (h < H) ? b2[h] : 0.0f;
#pragma unroll
        for (int q = 0; q < 4; ++q) {
            const int jl = tj * 4 + q;
            const float v = (h < H) ? fmaxf(acc2[q][m] + bb, 0.0f) : 0.0f;
            h2[jl * 161 + h] = v;
        }
    }
    __syncthreads();

    // ---- layer 3 + output: one thread per j ----
    if (tid < JB) {
        float s = b3[0];
        for (int h = 0; h < H; ++h) s = fmaf(h2[tid * 161 + h], W3[h], s);
        const int j = j0 + tid;
        out[i * N + j] = (ms[i] + ms[j] + s) * (1.0f / 3.0f);
    }
}

extern "C" void kernel_launch(void* const* d_in, const int* in_sizes, int n_in,
                              void* d_out, int out_size, void* d_ws, size_t ws_size,
                              hipStream_t stream) {
    const float* g  = (const float*)d_in[0];  // (1,512,256)
    const float* ms = (const float*)d_in[1];  // (1,512,1)
    const float* W1 = (const float*)d_in[2];  // (768,150)
    const float* b1 = (const float*)d_in[3];  // (150,)
    const float* W2 = (const float*)d_in[4];  // (150,150)
    const float* b2 = (const float*)d_in[5];  // (150,)
    const float* W3 = (const float*)d_in[6];  // (150,1)
    const float* b3 = (const float*)d_in[7];  // (1,)
    float* out = (float*)d_out;
    float* ws  = (float*)d_ws;                // needs 2*512*160*4 = 640 KB

    precompute_ab<<<N, 256, 0, stream>>>(g, W1, b1, ws);
    dim3 grid(N / JB, N);
    pairwise_main<<<grid, 256, 0, stream>>>(g, ms, W1, W2, b2, W3, b3, ws, out);
}

// Round 2
// 256.319 us; speedup vs baseline: 3.9800x; 3.9800x over previous
//
#include <hip/hip_runtime.h>

#define N  512
#define E  256
#define H  150
#define HP 160

typedef __attribute__((ext_vector_type(8))) short short8;   // 8 bf16 (4 VGPR)
typedef __attribute__((ext_vector_type(4))) float f32x4;

__device__ __forceinline__ unsigned short f2bf(float f) {
    unsigned u = __float_as_uint(f);
    u += 0x7fffu + ((u >> 16) & 1u);          // round-to-nearest-even
    return (unsigned short)(u >> 16);
}
__device__ __forceinline__ float bf2f(unsigned short s) {
    return __uint_as_float(((unsigned)s) << 16);
}

// ---------------- kernel 1: A[i,h]=g_i@W1a + b1 (f32), B[j,h]=g_j@W1b (bf16) ----------------
// ws: A f32 [512][160] at 0 ; B bf16 [512][160] at byte 512*160*4. Pads h>=150 zeroed.
__global__ __launch_bounds__(192) void precompute_ab(
    const float* __restrict__ g, const float* __restrict__ W1,
    const float* __restrict__ b1, float* __restrict__ wsA,
    unsigned short* __restrict__ wsB)
{
    const int i0  = blockIdx.x * 4;
    const int tid = threadIdx.x;
    __shared__ float gi[4][E];
    for (int idx = tid; idx < 4 * E; idx += 192) gi[idx >> 8][idx & 255] = g[i0 * E + idx];
    __syncthreads();
    const int h = tid;
    if (h < HP) {
        float a[4] = {0, 0, 0, 0}, b[4] = {0, 0, 0, 0};
        if (h < H) {
            for (int e = 0; e < E; ++e) {
                const float wa = W1[e * H + h];
                const float wb = W1[(E + e) * H + h];
#pragma unroll
                for (int qq = 0; qq < 4; ++qq) {
                    a[qq] = fmaf(gi[qq][e], wa, a[qq]);
                    b[qq] = fmaf(gi[qq][e], wb, b[qq]);
                }
            }
            const float bb = b1[h];
#pragma unroll
            for (int qq = 0; qq < 4; ++qq) a[qq] += bb;
        }
#pragma unroll
        for (int qq = 0; qq < 4; ++qq) {
            wsA[(i0 + qq) * HP + h] = a[qq];
            wsB[(i0 + qq) * HP + h] = f2bf(b[qq]);
        }
    }
}

// ---------------- kernel 2: fused pairwise MFMA MLP ----------------
#define JCH 128
#define PSTR 264            // P row stride, elems (528 B = 16*33, b128-aligned, 2-way bank)
#define H1STR 168           // h1 row stride, elems (336 B = 16*21)
#define OFF_P  0
#define SZ_P   (JCH * PSTR * 2)            // 67584
#define OFF_H1 (OFF_P + SZ_P)              // 67584
#define SZ_H1  (JCH * H1STR * 2)           // 43008
#define OFF_GI (OFF_H1 + SZ_H1)            // 110592
#define OFF_SB (OFF_GI + 1024)             // 111616
#define LDS_SZ (OFF_SB + 1024)             // 112640
// W1t transient: rows h (160) stride 528B at 0 (84480 B); W2t transient: stride 336B (53760 B)

__global__ __launch_bounds__(256, 1) void pairwise_mfma(
    const float* __restrict__ g,  const float* __restrict__ ms,
    const float* __restrict__ W1, const float* __restrict__ W2,
    const float* __restrict__ b2, const float* __restrict__ W3,
    const float* __restrict__ b3, const float* __restrict__ wsA,
    const unsigned short* __restrict__ wsB, float* __restrict__ out)
{
    __shared__ __attribute__((aligned(16))) char smem[LDS_SZ];
    const int tid  = threadIdx.x;
    const int wave = tid >> 6;
    const int lane = tid & 63;
    const int c    = lane & 15;     // n/m within tile
    const int q    = lane >> 4;     // quad
    const int jh   = wave & 1;      // j-half of chunk (64 j)
    const int hh   = wave >> 1;     // h-half (80 h)

    // ---- zero weight-staging region (covers pad rows/cols) ----
    for (int o = tid * 16; o < 84480; o += 256 * 16) *(f32x4*)(smem + o) = (f32x4){0, 0, 0, 0};
    __syncthreads();
    // ---- stage W1t[h][e] = W1c[e][h] as bf16, 2 e per iter, coalesced over h ----
    if (tid < H) {
        for (int ep = 0; ep < E / 2; ++ep) {
            unsigned short lo = f2bf(W1[(2 * E + 2 * ep) * H + tid]);
            unsigned short hi = f2bf(W1[(2 * E + 2 * ep + 1) * H + tid]);
            *(unsigned*)(smem + tid * 528 + ep * 4) = (unsigned)lo | ((unsigned)hi << 16);
        }
    }
    __syncthreads();
    short8 w1f[5][8];
#pragma unroll
    for (int m = 0; m < 5; ++m)
#pragma unroll
        for (int kt = 0; kt < 8; ++kt)
            w1f[m][kt] = *(const short8*)(smem + (hh * 80 + m * 16 + c) * 528 + (kt * 32 + q * 8) * 2);
    __syncthreads();
    // ---- stage W2t[ho][hi] = W2[hi][ho] ----
    for (int o = tid * 16; o < 53760; o += 256 * 16) *(f32x4*)(smem + o) = (f32x4){0, 0, 0, 0};
    __syncthreads();
    if (tid < H) {
        for (int kp = 0; kp < 75; ++kp) {
            unsigned short lo = f2bf(W2[(2 * kp) * H + tid]);
            unsigned short hi = f2bf(W2[(2 * kp + 1) * H + tid]);
            *(unsigned*)(smem + tid * 336 + kp * 4) = (unsigned)lo | ((unsigned)hi << 16);
        }
    }
    __syncthreads();
    short8 w2f[5][5];
#pragma unroll
    for (int m = 0; m < 5; ++m)
#pragma unroll
        for (int kt = 0; kt < 5; ++kt)
            w2f[m][kt] = *(const short8*)(smem + (hh * 80 + m * 16 + c) * 336 + (kt * 32 + q * 8) * 2);
    __syncthreads();

    // per-lane h-dependent constants
    float b2r[5], w3r[5];
#pragma unroll
    for (int m = 0; m < 5; ++m) {
        const int h = hh * 80 + m * 16 + c;
        b2r[m] = (h < H) ? b2[h] : 0.0f;
        w3r[m] = (h < H) ? W3[h] : 0.0f;
    }
    const float b3v = b3[0];

    for (int ii = 0; ii < 2; ++ii) {
        const int i = blockIdx.x * 2 + ii;
        if (tid < 64) *(f32x4*)(smem + OFF_GI + tid * 16) = ((const f32x4*)g)[i * 64 + tid];
        __syncthreads();
        const int e0 = (tid & 31) * 8;
        float gie[8];
#pragma unroll
        for (int x = 0; x < 8; ++x) gie[x] = *(const float*)(smem + OFF_GI + (e0 + x) * 4);
        float air[5];
#pragma unroll
        for (int m = 0; m < 5; ++m) air[m] = wsA[i * HP + hh * 80 + m * 16 + c];
        const float msi = ms[i];

        for (int chv = 0; chv < N / JCH; ++chv) {
            const int j0 = chv * JCH;
            // ---- stage P[jl][e] = gi[e]*g_j[e] (bf16) ----
            {
                const int jb = tid >> 5;
#pragma unroll
                for (int it = 0; it < 16; ++it) {
                    const int jl = jb + it * 8;
                    const float* gr = g + (j0 + jl) * E + e0;
                    short8 pk;
#pragma unroll
                    for (int x = 0; x < 8; ++x) pk[x] = (short)f2bf(gr[x] * gie[x]);
                    *(short8*)(smem + OFF_P + jl * 528 + e0 * 2) = pk;
                }
            }
            __syncthreads();
            // ---- layer 1 MFMA: acc[jt][m] over K=256 ----
            f32x4 acc[4][5];
#pragma unroll
            for (int jt = 0; jt < 4; ++jt)
#pragma unroll
                for (int m = 0; m < 5; ++m) acc[jt][m] = (f32x4){0, 0, 0, 0};
#pragma unroll
            for (int kt = 0; kt < 8; ++kt) {
                short8 a[4];
#pragma unroll
                for (int jt = 0; jt < 4; ++jt)
                    a[jt] = *(const short8*)(smem + OFF_P + (jh * 64 + jt * 16 + c) * 528 + (kt * 32 + q * 8) * 2);
#pragma unroll
                for (int jt = 0; jt < 4; ++jt)
#pragma unroll
                    for (int m = 0; m < 5; ++m)
                        acc[jt][m] = __builtin_amdgcn_mfma_f32_16x16x32_bf16(a[jt], w1f[m][kt], acc[jt][m], 0, 0, 0);
            }
            // ---- epilogue 1: h1 = relu(acc + A_i + B_j) -> LDS bf16 (A-layout) ----
#pragma unroll
            for (int jt = 0; jt < 4; ++jt)
#pragma unroll
                for (int m = 0; m < 5; ++m) {
                    const int h = hh * 80 + m * 16 + c;
#pragma unroll
                    for (int r = 0; r < 4; ++r) {
                        const int jl = jh * 64 + jt * 16 + q * 4 + r;
                        float v = acc[jt][m][r] + air[m] + bf2f(wsB[(j0 + jl) * HP + h]);
                        v = fmaxf(v, 0.0f);
                        *(unsigned short*)(smem + OFF_H1 + jl * 336 + h * 2) = f2bf(v);
                    }
                }
            __syncthreads();
            // ---- layer 2 MFMA: K=160 ----
            f32x4 acc2[4][5];
#pragma unroll
            for (int jt = 0; jt < 4; ++jt)
#pragma unroll
                for (int m = 0; m < 5; ++m) acc2[jt][m] = (f32x4){0, 0, 0, 0};
#pragma unroll
            for (int kt = 0; kt < 5; ++kt) {
                short8 a[4];
#pragma unroll
                for (int jt = 0; jt < 4; ++jt)
                    a[jt] = *(const short8*)(smem + OFF_H1 + (jh * 64 + jt * 16 + c) * 336 + (kt * 32 + q * 8) * 2);
#pragma unroll
                for (int jt = 0; jt < 4; ++jt)
#pragma unroll
                    for (int m = 0; m < 5; ++m)
                        acc2[jt][m] = __builtin_amdgcn_mfma_f32_16x16x32_bf16(a[jt], w2f[m][kt], acc2[jt][m], 0, 0, 0);
            }
            // ---- epilogue 2 + layer 3: s[j] = relu(acc2+b2) . W3 ----
#pragma unroll
            for (int jt = 0; jt < 4; ++jt) {
                float part[4] = {0, 0, 0, 0};
#pragma unroll
                for (int m = 0; m < 5; ++m)
#pragma unroll
                    for (int r = 0; r < 4; ++r)
                        part[r] = fmaf(fmaxf(acc2[jt][m][r] + b2r[m], 0.0f), w3r[m], part[r]);
#pragma unroll
                for (int r = 0; r < 4; ++r) {
                    float v = part[r];
                    v += __shfl_xor(v, 1);
                    v += __shfl_xor(v, 2);
                    v += __shfl_xor(v, 4);
                    v += __shfl_xor(v, 8);
                    if (c == 0) {
                        const int jl = jh * 64 + jt * 16 + q * 4 + r;
                        *(float*)(smem + OFF_SB + (hh * JCH + jl) * 4) = v;
                    }
                }
            }
            __syncthreads();
            // ---- combine halves + output ----
            if (tid < JCH) {
                const int j = j0 + tid;
                const float s = *(const float*)(smem + OFF_SB + tid * 4)
                              + *(const float*)(smem + OFF_SB + (JCH + tid) * 4) + b3v;
                out[i * N + j] = (msi + ms[j] + s) * (1.0f / 3.0f);
            }
            __syncthreads();
        }
    }
}

extern "C" void kernel_launch(void* const* d_in, const int* in_sizes, int n_in,
                              void* d_out, int out_size, void* d_ws, size_t ws_size,
                              hipStream_t stream) {
    const float* g  = (const float*)d_in[0];
    const float* ms = (const float*)d_in[1];
    const float* W1 = (const float*)d_in[2];
    const float* b1 = (const float*)d_in[3];
    const float* W2 = (const float*)d_in[4];
    const float* b2 = (const float*)d_in[5];
    const float* W3 = (const float*)d_in[6];
    const float* b3 = (const float*)d_in[7];
    float* out = (float*)d_out;
    float* wsA = (float*)d_ws;                                        // 512*160 f32
    unsigned short* wsB = (unsigned short*)((char*)d_ws + N * HP * 4); // 512*160 bf16

    precompute_ab<<<N / 4, 192, 0, stream>>>(g, W1, b1, wsA, wsB);
    pairwise_mfma<<<N / 2, 256, 0, stream>>>(g, ms, W1, W2, b2, W3, b3, wsA, wsB, out);
}

// Round 3
// 247.201 us; speedup vs baseline: 4.1268x; 1.0369x over previous
//
#include <hip/hip_runtime.h>

#define N  512
#define E  256
#define H  150
#define HP 160
#define JB 64          // j per chunk
#define NCH (N / JB)   // 8

typedef __attribute__((ext_vector_type(8))) short short8;
typedef __attribute__((ext_vector_type(4))) float f32x4;
typedef __attribute__((ext_vector_type(4))) unsigned uint4v;
typedef __attribute__((ext_vector_type(2))) unsigned uint2v;

__device__ __forceinline__ unsigned short f2bf(float f) {
    unsigned u = __float_as_uint(f);
    u += 0x7fffu + ((u >> 16) & 1u);          // RNE
    return (unsigned short)(u >> 16);
}
__device__ __forceinline__ unsigned pkbf(float a, float b) {
    return (unsigned)f2bf(a) | ((unsigned)f2bf(b) << 16);
}

// ---------------- kernel 1: A[i,h]=g_i@W1a + b1 (f32), B[j,h]=g_j@W1b (bf16) ----------------
__global__ __launch_bounds__(192) void precompute_ab(
    const float* __restrict__ g, const float* __restrict__ W1,
    const float* __restrict__ b1, float* __restrict__ wsA,
    unsigned short* __restrict__ wsB)
{
    const int i0  = blockIdx.x * 4;
    const int tid = threadIdx.x;
    __shared__ float gi[4][E];
    for (int idx = tid; idx < 4 * E; idx += 192) gi[idx >> 8][idx & 255] = g[i0 * E + idx];
    __syncthreads();
    const int h = tid;
    if (h < HP) {
        float a[4] = {0, 0, 0, 0}, b[4] = {0, 0, 0, 0};
        if (h < H) {
            for (int e = 0; e < E; ++e) {
                const float wa = W1[e * H + h];
                const float wb = W1[(E + e) * H + h];
#pragma unroll
                for (int qq = 0; qq < 4; ++qq) {
                    a[qq] = fmaf(gi[qq][e], wa, a[qq]);
                    b[qq] = fmaf(gi[qq][e], wb, b[qq]);
                }
            }
            const float bb = b1[h];
#pragma unroll
            for (int qq = 0; qq < 4; ++qq) a[qq] += bb;
        }
#pragma unroll
        for (int qq = 0; qq < 4; ++qq) {
            wsA[(i0 + qq) * HP + h] = a[qq];
            wsB[(i0 + qq) * HP + h] = f2bf(b[qq]);
        }
    }
}

// ---------------- kernel 2: fused pairwise MFMA MLP (D = h x j orientation) ----------------
// LDS layout (bytes):
#define OFF_P   0        // P  [64][528]  = 33792
#define OFF_H1  33792    // h1 [64][336]  = 21504
#define OFF_B   55296    // Bc [64][336]  = 21504
#define OFF_CC  76800    // b2l 160 f32   = 640
#define OFF_W3  77440    // w3l 160 f32   = 640
#define OFF_SB  78080    // sb  128 f32   = 512 -> 78592
#define LDS_SZ  79200    // W1t transient 150*528 = 79200 (overlaps all above)

__global__ __launch_bounds__(256, 2) void pairwise_mfma(
    const float* __restrict__ g,  const float* __restrict__ ms,
    const float* __restrict__ W1, const float* __restrict__ W2,
    const float* __restrict__ b2, const float* __restrict__ W3,
    const float* __restrict__ b3, const float* __restrict__ wsA,
    const unsigned short* __restrict__ wsB, float* __restrict__ out)
{
    __shared__ __attribute__((aligned(16))) char smem[LDS_SZ];
    float* smf = (float*)smem;
    const int tid  = threadIdx.x;
    const int wave = tid >> 6;
    const int lane = tid & 63;
    const int c    = lane & 15;     // tile col/row select
    const int q    = lane >> 4;     // quad
    const int jh   = wave & 1;      // j-half (32 j)
    const int hh   = wave >> 1;     // h-half (80 h)
    const int i    = blockIdx.x;

    // ---- stage W1t[h][e] bf16, stride 528B (transient, overlaps chunk regions) ----
    if (tid < H) {
        const float* wsrc = W1 + 2 * E * H + tid;
        char* dst = smem + tid * 528;
        for (int ep = 0; ep < E / 2; ++ep)
            *(unsigned*)(dst + ep * 4) = pkbf(wsrc[(2 * ep) * H], wsrc[(2 * ep + 1) * H]);
    }
    __syncthreads();
    short8 w1f[5][8];
    {
        const short8 z8 = {0, 0, 0, 0, 0, 0, 0, 0};
#pragma unroll
        for (int m = 0; m < 5; ++m) {
            const int hr = hh * 80 + m * 16 + c;
#pragma unroll
            for (int kt = 0; kt < 8; ++kt)
                w1f[m][kt] = (hr < H) ? *(const short8*)(smem + hr * 528 + (kt * 32 + q * 8) * 2) : z8;
        }
    }
    __syncthreads();
    // ---- stage W2t[h'][h] stride 336B + b2l/w3l (beyond W2t region) ----
    if (tid < H) {
        char* dst = smem + tid * 336;
        for (int kp = 0; kp < 80; ++kp) {
            const float lo = (2 * kp     < H) ? W2[(2 * kp) * H + tid]     : 0.0f;
            const float hi = (2 * kp + 1 < H) ? W2[(2 * kp + 1) * H + tid] : 0.0f;
            *(unsigned*)(dst + kp * 4) = pkbf(lo, hi);
        }
    }
    if (tid < HP) {
        smf[OFF_CC / 4 + tid] = (tid < H) ? b2[tid] : 0.0f;
        smf[OFF_W3 / 4 + tid] = (tid < H) ? W3[tid] : 0.0f;
    }
    __syncthreads();
    short8 w2f[5][5];
    {
        const short8 z8 = {0, 0, 0, 0, 0, 0, 0, 0};
#pragma unroll
        for (int m = 0; m < 5; ++m) {
            const int hr = hh * 80 + m * 16 + c;
#pragma unroll
            for (int kt = 0; kt < 5; ++kt)
                w2f[m][kt] = (hr < H) ? *(const short8*)(smem + hr * 336 + (kt * 32 + q * 8) * 2) : z8;
        }
    }
    __syncthreads();

    // per-thread constants
    const int e0 = (tid & 31) * 8;
    const int jb = tid >> 5;
    const f32x4 ga = *(const f32x4*)(g + i * E + e0);
    const f32x4 gb = *(const f32x4*)(g + i * E + e0 + 4);
    f32x4 air[5];
#pragma unroll
    for (int m = 0; m < 5; ++m) air[m] = *(const f32x4*)(wsA + i * HP + hh * 80 + m * 16 + q * 4);
    const float msi = ms[i];
    const float b3v = b3[0];

    for (int ch = 0; ch < NCH; ++ch) {
        const int j0 = ch * JB;
        // ---- stage B-chunk [64][336B], coalesced dwordx4 ----
        {
            const int jr = tid >> 2, qd = tid & 3;
            const uint4v* src = (const uint4v*)(wsB + (j0 + jr) * HP + qd * 40);
            uint4v* dst = (uint4v*)(smem + OFF_B + jr * 336 + qd * 80);
#pragma unroll
            for (int t = 0; t < 5; ++t) dst[t] = src[t];
            if (qd == 3) *(uint4v*)(smem + OFF_B + jr * 336 + 320) = (uint4v){0, 0, 0, 0};
        }
        // ---- stage P[jl][e] = gi*gj bf16 ----
#pragma unroll
        for (int it = 0; it < 8; ++it) {
            const int jl = jb + it * 8;
            const float* gr = g + (j0 + jl) * E + e0;
            const f32x4 u = *(const f32x4*)gr;
            const f32x4 v = *(const f32x4*)(gr + 4);
            uint4v pk;
            pk[0] = pkbf(u[0] * ga[0], u[1] * ga[1]);
            pk[1] = pkbf(u[2] * ga[2], u[3] * ga[3]);
            pk[2] = pkbf(v[0] * gb[0], v[1] * gb[1]);
            pk[3] = pkbf(v[2] * gb[2], v[3] * gb[3]);
            *(uint4v*)(smem + OFF_P + jl * 528 + e0 * 2) = pk;
        }
        __syncthreads();
        // ---- layer 1: D[h][j] = mfma(W1t-frag, P-frag) ----
        f32x4 acc[2][5];
#pragma unroll
        for (int jt = 0; jt < 2; ++jt)
#pragma unroll
            for (int m = 0; m < 5; ++m) acc[jt][m] = (f32x4){0, 0, 0, 0};
#pragma unroll
        for (int kt = 0; kt < 8; ++kt) {
            short8 pf[2];
#pragma unroll
            for (int jt = 0; jt < 2; ++jt)
                pf[jt] = *(const short8*)(smem + OFF_P + (jh * 32 + jt * 16 + c) * 528 + (kt * 32 + q * 8) * 2);
#pragma unroll
            for (int jt = 0; jt < 2; ++jt)
#pragma unroll
                for (int m = 0; m < 5; ++m)
                    acc[jt][m] = __builtin_amdgcn_mfma_f32_16x16x32_bf16(w1f[m][kt], pf[jt], acc[jt][m], 0, 0, 0);
        }
        // ---- epi 1: h1[j][h] = relu(acc + A_i[h] + B[j][h]), b64 LDS ops ----
#pragma unroll
        for (int jt = 0; jt < 2; ++jt) {
            const int j = jh * 32 + jt * 16 + c;
#pragma unroll
            for (int m = 0; m < 5; ++m) {
                const int h0 = hh * 80 + m * 16 + q * 4;
                const uint2v bv = *(const uint2v*)(smem + OFF_B + j * 336 + h0 * 2);
                const float v0 = fmaxf(acc[jt][m][0] + air[m][0] + __uint_as_float(bv[0] << 16), 0.0f);
                const float v1 = fmaxf(acc[jt][m][1] + air[m][1] + __uint_as_float(bv[0] & 0xffff0000u), 0.0f);
                const float v2 = fmaxf(acc[jt][m][2] + air[m][2] + __uint_as_float(bv[1] << 16), 0.0f);
                const float v3 = fmaxf(acc[jt][m][3] + air[m][3] + __uint_as_float(bv[1] & 0xffff0000u), 0.0f);
                uint2v hw;
                hw[0] = pkbf(v0, v1);
                hw[1] = pkbf(v2, v3);
                *(uint2v*)(smem + OFF_H1 + j * 336 + h0 * 2) = hw;
            }
        }
        __syncthreads();
        // ---- layer 2: D[h'][j] = mfma(W2t-frag, h1-frag) ----
        f32x4 acc2[2][5];
#pragma unroll
        for (int jt = 0; jt < 2; ++jt)
#pragma unroll
            for (int m = 0; m < 5; ++m) acc2[jt][m] = (f32x4){0, 0, 0, 0};
#pragma unroll
        for (int kt = 0; kt < 5; ++kt) {
            short8 hf[2];
#pragma unroll
            for (int jt = 0; jt < 2; ++jt)
                hf[jt] = *(const short8*)(smem + OFF_H1 + (jh * 32 + jt * 16 + c) * 336 + (kt * 32 + q * 8) * 2);
#pragma unroll
            for (int jt = 0; jt < 2; ++jt)
#pragma unroll
                for (int m = 0; m < 5; ++m)
                    acc2[jt][m] = __builtin_amdgcn_mfma_f32_16x16x32_bf16(w2f[m][kt], hf[jt], acc2[jt][m], 0, 0, 0);
        }
        // ---- epi 2 + layer 3 ----
        float part[2] = {0.0f, 0.0f};
#pragma unroll
        for (int m = 0; m < 5; ++m) {
            const f32x4 b2v = *(const f32x4*)(smf + OFF_CC / 4 + hh * 80 + m * 16 + q * 4);
            const f32x4 w3v = *(const f32x4*)(smf + OFF_W3 / 4 + hh * 80 + m * 16 + q * 4);
#pragma unroll
            for (int jt = 0; jt < 2; ++jt)
#pragma unroll
                for (int r = 0; r < 4; ++r)
                    part[jt] = fmaf(fmaxf(acc2[jt][m][r] + b2v[r], 0.0f), w3v[r], part[jt]);
        }
#pragma unroll
        for (int jt = 0; jt < 2; ++jt) {
            float p = part[jt];
            p += __shfl_xor(p, 16);
            p += __shfl_xor(p, 32);
            if (q == 0) smf[OFF_SB / 4 + hh * 64 + jh * 32 + jt * 16 + c] = p;
        }
        __syncthreads();
        if (tid < JB) {
            const int j = j0 + tid;
            const float s = smf[OFF_SB / 4 + tid] + smf[OFF_SB / 4 + 64 + tid] + b3v;
            out[i * N + j] = (msi + ms[j] + s) * (1.0f / 3.0f);
        }
        __syncthreads();
    }
}

extern "C" void kernel_launch(void* const* d_in, const int* in_sizes, int n_in,
                              void* d_out, int out_size, void* d_ws, size_t ws_size,
                              hipStream_t stream) {
    const float* g  = (const float*)d_in[0];
    const float* ms = (const float*)d_in[1];
    const float* W1 = (const float*)d_in[2];
    const float* b1 = (const float*)d_in[3];
    const float* W2 = (const float*)d_in[4];
    const float* b2 = (const float*)d_in[5];
    const float* W3 = (const float*)d_in[6];
    const float* b3 = (const float*)d_in[7];
    float* out = (float*)d_out;
    float* wsA = (float*)d_ws;                                         // 512*160 f32
    unsigned short* wsB = (unsigned short*)((char*)d_ws + N * HP * 4); // 512*160 bf16

    precompute_ab<<<N / 4, 192, 0, stream>>>(g, W1, b1, wsA, wsB);
    pairwise_mfma<<<N, 256, 0, stream>>>(g, ms, W1, W2, b2, W3, b3, wsA, wsB, out);
}

// Round 6
// 230.099 us; speedup vs baseline: 4.4335x; 1.0743x over previous
//
#include <hip/hip_runtime.h>

#define N  512
#define E  256
#define H  150
#define HP 160
#define JB 64          // j per chunk
#define NCH (N / JB)   // 8

typedef __attribute__((ext_vector_type(8))) short short8;
typedef __attribute__((ext_vector_type(4))) float f32x4;
typedef __attribute__((ext_vector_type(4))) unsigned uint4v;
typedef __attribute__((ext_vector_type(2))) unsigned uint2v;

// Manual RNE f32->bf16 (verified R3 numerics; do not swap for intrinsics).
__device__ __forceinline__ unsigned short f2bf(float f) {
    unsigned u = __float_as_uint(f);
    u += 0x7fffu + ((u >> 16) & 1u);          // RNE
    return (unsigned short)(u >> 16);
}
__device__ __forceinline__ unsigned pkbf(float a, float b) {
    return (unsigned)f2bf(a) | ((unsigned)f2bf(b) << 16);
}

// ---------------- kernel 1: A[i,h]=g_i@W1a + b1 (f32), B[j,h]=g_j@W1b (bf16) ----------------
__global__ __launch_bounds__(192) void precompute_ab(
    const float* __restrict__ g, const float* __restrict__ W1,
    const float* __restrict__ b1, float* __restrict__ wsA,
    unsigned short* __restrict__ wsB)
{
    const int i0  = blockIdx.x * 4;
    const int tid = threadIdx.x;
    __shared__ float gi[4][E];
    for (int idx = tid; idx < 4 * E; idx += 192) gi[idx >> 8][idx & 255] = g[i0 * E + idx];
    __syncthreads();
    const int h = tid;
    if (h < HP) {
        float a[4] = {0, 0, 0, 0}, b[4] = {0, 0, 0, 0};
        if (h < H) {
            for (int e = 0; e < E; ++e) {
                const float wa = W1[e * H + h];
                const float wb = W1[(E + e) * H + h];
#pragma unroll
                for (int qq = 0; qq < 4; ++qq) {
                    a[qq] = fmaf(gi[qq][e], wa, a[qq]);
                    b[qq] = fmaf(gi[qq][e], wb, b[qq]);
                }
            }
            const float bb = b1[h];
#pragma unroll
            for (int qq = 0; qq < 4; ++qq) a[qq] += bb;
        }
#pragma unroll
        for (int qq = 0; qq < 4; ++qq) {
            wsA[(i0 + qq) * HP + h] = a[qq];
            wsB[(i0 + qq) * HP + h] = f2bf(b[qq]);
        }
    }
}

// ---------------- kernel 2: fused pairwise MFMA MLP (D = h x j orientation) ----------------
// LDS layout (bytes):
#define OFF_P   0        // P  [64][528]  = 33792
#define OFF_H1  33792    // h1 [64][336]  = 21504
#define OFF_B   55296    // Bc [64][336]  = 21504
#define OFF_CC  76800    // b2l 160 f32   = 640
#define OFF_W3  77440    // w3l 160 f32   = 640
#define OFF_SB  78080    // sb  128 f32   = 512 -> 78592
#define LDS_SZ  79200    // W1t transient 150*528 = 79200 (overlaps all above)

// __launch_bounds__(256, 1): R3 ran (256,2) -> VGPR capped at 128 vs ~340 demand
// (w1f 160 + w2f 100 + acc 40) -> scratch spill thrash (262 MB FETCH, 66 MB WRITE).
// Cap 512 removes the spill; LDS 79 KB means 1 block/CU either way at no-spill regs.
__global__ __launch_bounds__(256, 1) void pairwise_mfma(
    const float* __restrict__ g,  const float* __restrict__ ms,
    const float* __restrict__ W1, const float* __restrict__ W2,
    const float* __restrict__ b2, const float* __restrict__ W3,
    const float* __restrict__ b3, const float* __restrict__ wsA,
    const unsigned short* __restrict__ wsB, float* __restrict__ out)
{
    __shared__ __attribute__((aligned(16))) char smem[LDS_SZ];
    float* smf = (float*)smem;
    const int tid  = threadIdx.x;
    const int wave = tid >> 6;
    const int lane = tid & 63;
    const int c    = lane & 15;     // tile col/row select
    const int q    = lane >> 4;     // quad
    const int jh   = wave & 1;      // j-half (32 j)
    const int hh   = wave >> 1;     // h-half (80 h)
    const int i    = blockIdx.x;

    // ---- stage W1t[h][e] bf16, stride 528B (transient, overlaps chunk regions) ----
    if (tid < H) {
        const float* wsrc = W1 + 2 * E * H + tid;
        char* dst = smem + tid * 528;
        for (int ep = 0; ep < E / 2; ++ep)
            *(unsigned*)(dst + ep * 4) = pkbf(wsrc[(2 * ep) * H], wsrc[(2 * ep + 1) * H]);
    }
    __syncthreads();
    short8 w1f[5][8];
    {
        const short8 z8 = {0, 0, 0, 0, 0, 0, 0, 0};
#pragma unroll
        for (int m = 0; m < 5; ++m) {
            const int hr = hh * 80 + m * 16 + c;
#pragma unroll
            for (int kt = 0; kt < 8; ++kt)
                w1f[m][kt] = (hr < H) ? *(const short8*)(smem + hr * 528 + (kt * 32 + q * 8) * 2) : z8;
        }
    }
    __syncthreads();
    // ---- stage W2t[h'][h] stride 336B + b2l/w3l (beyond W2t region) ----
    if (tid < H) {
        char* dst = smem + tid * 336;
        for (int kp = 0; kp < 80; ++kp) {
            const float lo = (2 * kp     < H) ? W2[(2 * kp) * H + tid]     : 0.0f;
            const float hi = (2 * kp + 1 < H) ? W2[(2 * kp + 1) * H + tid] : 0.0f;
            *(unsigned*)(dst + kp * 4) = pkbf(lo, hi);
        }
    }
    if (tid < HP) {
        smf[OFF_CC / 4 + tid] = (tid < H) ? b2[tid] : 0.0f;
        smf[OFF_W3 / 4 + tid] = (tid < H) ? W3[tid] : 0.0f;
    }
    __syncthreads();
    short8 w2f[5][5];
    {
        const short8 z8 = {0, 0, 0, 0, 0, 0, 0, 0};
#pragma unroll
        for (int m = 0; m < 5; ++m) {
            const int hr = hh * 80 + m * 16 + c;
#pragma unroll
            for (int kt = 0; kt < 5; ++kt)
                w2f[m][kt] = (hr < H) ? *(const short8*)(smem + hr * 336 + (kt * 32 + q * 8) * 2) : z8;
        }
    }
    __syncthreads();

    // per-thread constants
    const int e0 = (tid & 31) * 8;
    const int jb = tid >> 5;
    const f32x4 ga = *(const f32x4*)(g + i * E + e0);
    const f32x4 gb = *(const f32x4*)(g + i * E + e0 + 4);
    f32x4 air[5];
#pragma unroll
    for (int m = 0; m < 5; ++m) air[m] = *(const f32x4*)(wsA + i * HP + hh * 80 + m * 16 + q * 4);
    const float msi = ms[i];
    const float b3v = b3[0];

    for (int ch = 0; ch < NCH; ++ch) {
        const int j0 = ch * JB;
        // ---- stage B-chunk [64][336B], coalesced dwordx4 ----
        {
            const int jr = tid >> 2, qd = tid & 3;
            const uint4v* src = (const uint4v*)(wsB + (j0 + jr) * HP + qd * 40);
            uint4v* dst = (uint4v*)(smem + OFF_B + jr * 336 + qd * 80);
#pragma unroll
            for (int t = 0; t < 5; ++t) dst[t] = src[t];
            if (qd == 3) *(uint4v*)(smem + OFF_B + jr * 336 + 320) = (uint4v){0, 0, 0, 0};
        }
        // ---- stage P[jl][e] = gi*gj bf16 ----
#pragma unroll
        for (int it = 0; it < 8; ++it) {
            const int jl = jb + it * 8;
            const float* gr = g + (j0 + jl) * E + e0;
            const f32x4 u = *(const f32x4*)gr;
            const f32x4 v = *(const f32x4*)(gr + 4);
            uint4v pk;
            pk[0] = pkbf(u[0] * ga[0], u[1] * ga[1]);
            pk[1] = pkbf(u[2] * ga[2], u[3] * ga[3]);
            pk[2] = pkbf(v[0] * gb[0], v[1] * gb[1]);
            pk[3] = pkbf(v[2] * gb[2], v[3] * gb[3]);
            *(uint4v*)(smem + OFF_P + jl * 528 + e0 * 2) = pk;
        }
        __syncthreads();
        // ---- layer 1: D[h][j] = mfma(W1t-frag, P-frag) ----
        f32x4 acc[2][5];
#pragma unroll
        for (int jt = 0; jt < 2; ++jt)
#pragma unroll
            for (int m = 0; m < 5; ++m) acc[jt][m] = (f32x4){0, 0, 0, 0};
#pragma unroll
        for (int kt = 0; kt < 8; ++kt) {
            short8 pf[2];
#pragma unroll
            for (int jt = 0; jt < 2; ++jt)
                pf[jt] = *(const short8*)(smem + OFF_P + (jh * 32 + jt * 16 + c) * 528 + (kt * 32 + q * 8) * 2);
#pragma unroll
            for (int jt = 0; jt < 2; ++jt)
#pragma unroll
                for (int m = 0; m < 5; ++m)
                    acc[jt][m] = __builtin_amdgcn_mfma_f32_16x16x32_bf16(w1f[m][kt], pf[jt], acc[jt][m], 0, 0, 0);
        }
        // ---- epi 1: h1[j][h] = relu(acc + A_i[h] + B[j][h]), b64 LDS ops ----
#pragma unroll
        for (int jt = 0; jt < 2; ++jt) {
            const int j = jh * 32 + jt * 16 + c;
#pragma unroll
            for (int m = 0; m < 5; ++m) {
                const int h0 = hh * 80 + m * 16 + q * 4;
                const uint2v bv = *(const uint2v*)(smem + OFF_B + j * 336 + h0 * 2);
                const float v0 = fmaxf(acc[jt][m][0] + air[m][0] + __uint_as_float(bv[0] << 16), 0.0f);
                const float v1 = fmaxf(acc[jt][m][1] + air[m][1] + __uint_as_float(bv[0] & 0xffff0000u), 0.0f);
                const float v2 = fmaxf(acc[jt][m][2] + air[m][2] + __uint_as_float(bv[1] << 16), 0.0f);
                const float v3 = fmaxf(acc[jt][m][3] + air[m][3] + __uint_as_float(bv[1] & 0xffff0000u), 0.0f);
                uint2v hw;
                hw[0] = pkbf(v0, v1);
                hw[1] = pkbf(v2, v3);
                *(uint2v*)(smem + OFF_H1 + j * 336 + h0 * 2) = hw;
            }
        }
        __syncthreads();
        // ---- layer 2: D[h'][j] = mfma(W2t-frag, h1-frag) ----
        f32x4 acc2[2][5];
#pragma unroll
        for (int jt = 0; jt < 2; ++jt)
#pragma unroll
            for (int m = 0; m < 5; ++m) acc2[jt][m] = (f32x4){0, 0, 0, 0};
#pragma unroll
        for (int kt = 0; kt < 5; ++kt) {
            short8 hf[2];
#pragma unroll
            for (int jt = 0; jt < 2; ++jt)
                hf[jt] = *(const short8*)(smem + OFF_H1 + (jh * 32 + jt * 16 + c) * 336 + (kt * 32 + q * 8) * 2);
#pragma unroll
            for (int jt = 0; jt < 2; ++jt)
#pragma unroll
                for (int m = 0; m < 5; ++m)
                    acc2[jt][m] = __builtin_amdgcn_mfma_f32_16x16x32_bf16(w2f[m][kt], hf[jt], acc2[jt][m], 0, 0, 0);
        }
        // ---- epi 2 + layer 3 ----
        float part[2] = {0.0f, 0.0f};
#pragma unroll
        for (int m = 0; m < 5; ++m) {
            const f32x4 b2v = *(const f32x4*)(smf + OFF_CC / 4 + hh * 80 + m * 16 + q * 4);
            const f32x4 w3v = *(const f32x4*)(smf + OFF_W3 / 4 + hh * 80 + m * 16 + q * 4);
#pragma unroll
            for (int jt = 0; jt < 2; ++jt)
#pragma unroll
                for (int r = 0; r < 4; ++r)
                    part[jt] = fmaf(fmaxf(acc2[jt][m][r] + b2v[r], 0.0f), w3v[r], part[jt]);
        }
#pragma unroll
        for (int jt = 0; jt < 2; ++jt) {
            float p = part[jt];
            p += __shfl_xor(p, 16);
            p += __shfl_xor(p, 32);
            if (q == 0) smf[OFF_SB / 4 + hh * 64 + jh * 32 + jt * 16 + c] = p;
        }
        __syncthreads();
        if (tid < JB) {
            const int j = j0 + tid;
            const float s = smf[OFF_SB / 4 + tid] + smf[OFF_SB / 4 + 64 + tid] + b3v;
            out[i * N + j] = (msi + ms[j] + s) * (1.0f / 3.0f);
        }
        __syncthreads();
    }
}

extern "C" void kernel_launch(void* const* d_in, const int* in_sizes, int n_in,
                              void* d_out, int out_size, void* d_ws, size_t ws_size,
                              hipStream_t stream) {
    const float* g  = (const float*)d_in[0];
    const float* ms = (const float*)d_in[1];
    const float* W1 = (const float*)d_in[2];
    const float* b1 = (const float*)d_in[3];
    const float* W2 = (const float*)d_in[4];
    const float* b2 = (const float*)d_in[5];
    const float* W3 = (const float*)d_in[6];
    const float* b3 = (const float*)d_in[7];
    float* out = (float*)d_out;
    float* wsA = (float*)d_ws;                                         // 512*160 f32
    unsigned short* wsB = (unsigned short*)((char*)d_ws + N * HP * 4); // 512*160 bf16

    precompute_ab<<<N / 4, 192, 0, stream>>>(g, W1, b1, wsA, wsB);
    pairwise_mfma<<<N, 256, 0, stream>>>(g, ms, W1, W2, b2, W3, b3, wsA, wsB, out);
}

// Round 7
// 169.294 us; speedup vs baseline: 6.0259x; 1.3592x over previous
//
#include <hip/hip_runtime.h>

#define N  512
#define E  256
#define H  150
#define HP 160
#define JB 64          // j per chunk
#define NCH (N / JB)   // 8

typedef __attribute__((ext_vector_type(8))) short short8;
typedef __attribute__((ext_vector_type(4))) float f32x4;
typedef __attribute__((ext_vector_type(4))) unsigned uint4v;
typedef __attribute__((ext_vector_type(2))) unsigned uint2v;

// Manual RNE f32->bf16 (verified numerics; __float22bfloat162_rn truncates here).
__device__ __forceinline__ unsigned short f2bf(float f) {
    unsigned u = __float_as_uint(f);
    u += 0x7fffu + ((u >> 16) & 1u);          // RNE
    return (unsigned short)(u >> 16);
}
__device__ __forceinline__ unsigned pkbf(float a, float b) {
    return (unsigned)f2bf(a) | ((unsigned)f2bf(b) << 16);
}

// ---------------- kernel 1: A[i,h]=g_i@W1a + b1 (f32), B[j,h]=g_j@W1b (bf16) ----------------
__global__ __launch_bounds__(192) void precompute_ab(
    const float* __restrict__ g, const float* __restrict__ W1,
    const float* __restrict__ b1, float* __restrict__ wsA,
    unsigned short* __restrict__ wsB)
{
    const int i0  = blockIdx.x * 4;
    const int tid = threadIdx.x;
    __shared__ float gi[4][E];
    for (int idx = tid; idx < 4 * E; idx += 192) gi[idx >> 8][idx & 255] = g[i0 * E + idx];
    __syncthreads();
    const int h = tid;
    if (h < HP) {
        float a[4] = {0, 0, 0, 0}, b[4] = {0, 0, 0, 0};
        if (h < H) {
            for (int e = 0; e < E; ++e) {
                const float wa = W1[e * H + h];
                const float wb = W1[(E + e) * H + h];
#pragma unroll
                for (int qq = 0; qq < 4; ++qq) {
                    a[qq] = fmaf(gi[qq][e], wa, a[qq]);
                    b[qq] = fmaf(gi[qq][e], wb, b[qq]);
                }
            }
            const float bb = b1[h];
#pragma unroll
            for (int qq = 0; qq < 4; ++qq) a[qq] += bb;
        }
#pragma unroll
        for (int qq = 0; qq < 4; ++qq) {
            wsA[(i0 + qq) * HP + h] = a[qq];
            wsB[(i0 + qq) * HP + h] = f2bf(b[qq]);
        }
    }
}

// ---------------- kernel 2: fused pairwise MFMA MLP ----------------
// 512 threads = 8 waves = 4 h-quarters x 2 j-halves. 2 i's per block (grid 256).
// h-quarter partition {0-47, 48-95, 96-127, 128-159} — EXACT partition.
// (R4 bug: hbase=(wq<3)?wq*48:128 made wq2/wq3 overlap at h 128-143 -> those 16
//  hidden units double-counted in the layer-3 cross-wave sum -> absmax 0.084.)
#define OFF_P   0        // P  [64][528B] = 33792
#define OFF_H1  33792    // h1 [64][336B] = 21504 -> 55296
#define OFF_C2  55296    // b2 160 f32 = 640 -> 55936
#define OFF_W3L 55936    // W3 160 f32 = 640 -> 56576
#define OFF_SB  56576    // 4x64 f32 = 1024 -> 57600
#define LDS_SZ  57600
// transients (before chunk loop): W1t [150][272B]=40800, W2t [150][336B]=50400 — both < OFF_C2

__global__ __launch_bounds__(512, 2) void pairwise_mfma(
    const float* __restrict__ g,  const float* __restrict__ ms,
    const float* __restrict__ W1, const float* __restrict__ W2,
    const float* __restrict__ b2, const float* __restrict__ W3,
    const float* __restrict__ b3, const float* __restrict__ wsA,
    const unsigned short* __restrict__ wsB, float* __restrict__ out)
{
    __shared__ __attribute__((aligned(16))) char smem[LDS_SZ];
    float* smf = (float*)smem;
    const int tid  = threadIdx.x;
    const int wave = tid >> 6;
    const int lane = tid & 63;
    const int c    = lane & 15;
    const int q    = lane >> 4;
    const int wq   = wave & 3;      // h-quarter
    const int jh   = wave >> 2;     // j-half (32 j)
    const int hbase  = (wq < 2) ? wq * 48 : 96 + (wq - 2) * 32;
    const int mcount = (wq < 2) ? 3 : 2;
    const short8 z8 = {0, 0, 0, 0, 0, 0, 0, 0};

    // ---- stage W1t (bf16 transposed, stride 272B) in 2 e-passes; 300 threads ----
    short8 w1f[3][8];
    for (int p = 0; p < 2; ++p) {
        if (p) __syncthreads();
        if (tid < 300) {
            const int h = (tid < 150) ? tid : tid - 150;
            const int half = (tid < 150) ? 0 : 1;
            const float* wsrc = W1 + (2 * E + p * 128) * H + h;
            char* dst = smem + h * 272 + half * 128;
#pragma unroll 4
            for (int t = 0; t < 32; ++t) {
                const int ep = half * 32 + t;
                *(unsigned*)(dst + t * 4) = pkbf(wsrc[(2 * ep) * H], wsrc[(2 * ep + 1) * H]);
            }
        }
        __syncthreads();
#pragma unroll
        for (int m = 0; m < 3; ++m) {
            const int hr = hbase + m * 16 + c;
#pragma unroll
            for (int ktp = 0; ktp < 4; ++ktp)
                w1f[m][p * 4 + ktp] = (m < mcount && hr < H)
                    ? *(const short8*)(smem + hr * 272 + (ktp * 32 + q * 8) * 2) : z8;
        }
    }
    __syncthreads();
    // ---- stage W2t (stride 336B); 300 threads; consts in parallel ----
    if (tid < 300) {
        const int h = (tid < 150) ? tid : tid - 150;
        const int half = (tid < 150) ? 0 : 1;
        char* dst = smem + h * 336;
#pragma unroll 4
        for (int t = 0; t < 42; ++t) {
            const int kp = half * 42 + t;
            const float lo = (2 * kp     < H) ? W2[(2 * kp) * H + h]     : 0.0f;
            const float hi = (2 * kp + 1 < H) ? W2[(2 * kp + 1) * H + h] : 0.0f;
            *(unsigned*)(dst + kp * 4) = pkbf(lo, hi);
        }
    }
    if (tid >= 320 && tid < 480) {
        const int hx = tid - 320;
        smf[OFF_C2 / 4 + hx]  = (hx < H) ? b2[hx] : 0.0f;
        smf[OFF_W3L / 4 + hx] = (hx < H) ? W3[hx] : 0.0f;
    }
    __syncthreads();
    short8 w2f[3][5];
#pragma unroll
    for (int m = 0; m < 3; ++m) {
        const int hr = hbase + m * 16 + c;
#pragma unroll
        for (int kt = 0; kt < 5; ++kt)
            w2f[m][kt] = (m < mcount && hr < H)
                ? *(const short8*)(smem + hr * 336 + (kt * 32 + q * 8) * 2) : z8;
    }
    __syncthreads();

    const int jb = tid >> 5;        // 0..15
    const int e0 = (tid & 31) * 8;
    const float b3v = b3[0];

    for (int ii = 0; ii < 2; ++ii) {
        const int i = blockIdx.x * 2 + ii;
        const f32x4 ga = *(const f32x4*)(g + i * E + e0);
        const f32x4 gb = *(const f32x4*)(g + i * E + e0 + 4);
        f32x4 av[3];
#pragma unroll
        for (int m = 0; m < 3; ++m)
            av[m] = (m < mcount) ? *(const f32x4*)(wsA + i * HP + hbase + m * 16 + q * 4)
                                 : (f32x4){0, 0, 0, 0};
        const float msi = ms[i];

        for (int ch = 0; ch < NCH; ++ch) {
            const int j0 = ch * JB;
            // ---- stage P[jl][e] = gi*gj bf16 (4 rows/thread) ----
#pragma unroll
            for (int it = 0; it < 4; ++it) {
                const int jl = jb + it * 16;
                const float* gr = g + (j0 + jl) * E + e0;
                const f32x4 u = *(const f32x4*)gr;
                const f32x4 v = *(const f32x4*)(gr + 4);
                uint4v pk;
                pk[0] = pkbf(u[0] * ga[0], u[1] * ga[1]);
                pk[1] = pkbf(u[2] * ga[2], u[3] * ga[3]);
                pk[2] = pkbf(v[0] * gb[0], v[1] * gb[1]);
                pk[3] = pkbf(v[2] * gb[2], v[3] * gb[3]);
                *(uint4v*)(smem + OFF_P + jl * 528 + e0 * 2) = pk;
            }
            __syncthreads();

            // ---- layer 1: D[h][j] = mfma(w1f, P-frag) ----
            f32x4 acc[2][3];
#pragma unroll
            for (int jt = 0; jt < 2; ++jt)
#pragma unroll
                for (int m = 0; m < 3; ++m) acc[jt][m] = (f32x4){0, 0, 0, 0};
#pragma unroll
            for (int kt = 0; kt < 8; ++kt) {
                short8 pf[2];
#pragma unroll
                for (int jt = 0; jt < 2; ++jt)
                    pf[jt] = *(const short8*)(smem + OFF_P + (jh * 32 + jt * 16 + c) * 528 + (kt * 32 + q * 8) * 2);
#pragma unroll
                for (int m = 0; m < 3; ++m)
                    if (m < mcount)
#pragma unroll
                        for (int jt = 0; jt < 2; ++jt)
                            acc[jt][m] = __builtin_amdgcn_mfma_f32_16x16x32_bf16(w1f[m][kt], pf[jt], acc[jt][m], 0, 0, 0);
            }
            // ---- epi 1: h1[j][h] = relu(acc + A_i[h] + B[j][h]) ----
#pragma unroll
            for (int m = 0; m < 3; ++m)
                if (m < mcount) {
                    const int h0 = hbase + m * 16 + q * 4;
#pragma unroll
                    for (int jt = 0; jt < 2; ++jt) {
                        const int j = jh * 32 + jt * 16 + c;
                        const uint2v bv = *(const uint2v*)(wsB + (j0 + j) * HP + h0);
                        const float v0 = fmaxf(acc[jt][m][0] + av[m][0] + __uint_as_float(bv[0] << 16), 0.0f);
                        const float v1 = fmaxf(acc[jt][m][1] + av[m][1] + __uint_as_float(bv[0] & 0xffff0000u), 0.0f);
                        const float v2 = fmaxf(acc[jt][m][2] + av[m][2] + __uint_as_float(bv[1] << 16), 0.0f);
                        const float v3 = fmaxf(acc[jt][m][3] + av[m][3] + __uint_as_float(bv[1] & 0xffff0000u), 0.0f);
                        uint2v hw;
                        hw[0] = pkbf(v0, v1);
                        hw[1] = pkbf(v2, v3);
                        *(uint2v*)(smem + OFF_H1 + j * 336 + h0 * 2) = hw;
                    }
                }
            __syncthreads();

            // ---- layer 2: reuse acc ----
#pragma unroll
            for (int jt = 0; jt < 2; ++jt)
#pragma unroll
                for (int m = 0; m < 3; ++m) acc[jt][m] = (f32x4){0, 0, 0, 0};
#pragma unroll
            for (int kt = 0; kt < 5; ++kt) {
                short8 hf[2];
#pragma unroll
                for (int jt = 0; jt < 2; ++jt)
                    hf[jt] = *(const short8*)(smem + OFF_H1 + (jh * 32 + jt * 16 + c) * 336 + (kt * 32 + q * 8) * 2);
#pragma unroll
                for (int m = 0; m < 3; ++m)
                    if (m < mcount)
#pragma unroll
                        for (int jt = 0; jt < 2; ++jt)
                            acc[jt][m] = __builtin_amdgcn_mfma_f32_16x16x32_bf16(w2f[m][kt], hf[jt], acc[jt][m], 0, 0, 0);
            }
            // ---- epi 2 + layer 3 ----
            float part[2] = {0.0f, 0.0f};
#pragma unroll
            for (int m = 0; m < 3; ++m)
                if (m < mcount) {
                    const int h0 = hbase + m * 16 + q * 4;
                    const f32x4 b2v = *(const f32x4*)(smf + OFF_C2 / 4 + h0);
                    const f32x4 w3v = *(const f32x4*)(smf + OFF_W3L / 4 + h0);
#pragma unroll
                    for (int jt = 0; jt < 2; ++jt)
#pragma unroll
                        for (int r = 0; r < 4; ++r)
                            part[jt] = fmaf(fmaxf(acc[jt][m][r] + b2v[r], 0.0f), w3v[r], part[jt]);
                }
#pragma unroll
            for (int jt = 0; jt < 2; ++jt) {
                float pv = part[jt];
                pv += __shfl_xor(pv, 16);
                pv += __shfl_xor(pv, 32);
                if (q == 0) smf[OFF_SB / 4 + wq * 64 + jh * 32 + jt * 16 + c] = pv;
            }
            __syncthreads();
            if (tid < JB) {
                const int j = j0 + tid;
                const float s = smf[OFF_SB / 4 + tid] + smf[OFF_SB / 4 + 64 + tid]
                              + smf[OFF_SB / 4 + 128 + tid] + smf[OFF_SB / 4 + 192 + tid] + b3v;
                out[i * N + j] = (msi + ms[j] + s) * (1.0f / 3.0f);
            }
            __syncthreads();
        }
    }
}

extern "C" void kernel_launch(void* const* d_in, const int* in_sizes, int n_in,
                              void* d_out, int out_size, void* d_ws, size_t ws_size,
                              hipStream_t stream) {
    const float* g  = (const float*)d_in[0];
    const float* ms = (const float*)d_in[1];
    const float* W1 = (const float*)d_in[2];
    const float* b1 = (const float*)d_in[3];
    const float* W2 = (const float*)d_in[4];
    const float* b2 = (const float*)d_in[5];
    const float* W3 = (const float*)d_in[6];
    const float* b3 = (const float*)d_in[7];
    float* out = (float*)d_out;
    float* wsA = (float*)d_ws;                                         // 512*160 f32
    unsigned short* wsB = (unsigned short*)((char*)d_ws + N * HP * 4); // 512*160 bf16

    precompute_ab<<<N / 4, 192, 0, stream>>>(g, W1, b1, wsA, wsB);
    pairwise_mfma<<<N / 2, 512, 0, stream>>>(g, ms, W1, W2, b2, W3, b3, wsA, wsB, out);
}